// Round 3
// baseline (370.165 us; speedup 1.0000x reference)
//
#include <hip/hip_runtime.h>

typedef __attribute__((ext_vector_type(8))) short  short8v;
typedef __attribute__((ext_vector_type(4))) float  float4v;

#define BDIM 512

// Pre-converted, pre-swizzled bf16 weights: [p(3)][kb(8)][n(256)][c(8)][j(8)]
// content: B_p[n][kb*64 + (c ^ (n&7))*8 + j], B_p = [W_p | U_p] (K-concat, 512 wide)
__device__ ushort g_w[3 * 8 * 2048 * 8];

__device__ __forceinline__ ushort f2bf(float f) {
  unsigned u = __float_as_uint(f);
  u += 0x7fffu + ((u >> 16) & 1u);          // round-to-nearest-even
  return (ushort)(u >> 16);
}
__device__ __forceinline__ float bf2f(ushort s) {
  return __uint_as_float(((unsigned)s) << 16);
}

__global__ __launch_bounds__(256) void conv_w(
    const float* __restrict__ Wz, const float* __restrict__ Uz,
    const float* __restrict__ Wa, const float* __restrict__ Ua,
    const float* __restrict__ Wh, const float* __restrict__ Uh)
{
  int tid = blockIdx.x * 256 + threadIdx.x;   // 49152 total
  int p  = tid >> 14;
  int rm = tid & 16383;
  int kb = rm >> 11;
  int n  = (rm >> 3) & 255;
  int c  = rm & 7;
  const float* W = (p == 0) ? Wz : (p == 1) ? Wa : Wh;
  const float* U = (p == 0) ? Uz : (p == 1) ? Ua : Uh;
  int k0 = kb * 64 + ((c ^ (n & 7)) << 3);    // 8-aligned, never straddles 256
  const float* src = (k0 < 256) ? (W + n * 256 + k0) : (U + n * 256 + k0 - 256);
  uint pk[4];
#pragma unroll
  for (int jj = 0; jj < 4; ++jj) {
    float v0 = src[jj * 2], v1 = src[jj * 2 + 1];
    pk[jj] = (uint)f2bf(v0) | ((uint)f2bf(v1) << 16);
  }
  *reinterpret_cast<uint4*>(&g_w[(size_t)tid * 8]) = make_uint4(pk[0], pk[1], pk[2], pk[3]);
}

__global__ __launch_bounds__(BDIM, 2) void gru_fused(
    const float* __restrict__ x,  const float* __restrict__ hp,
    const float* __restrict__ bz, const float* __restrict__ va,
    const float* __restrict__ bh, float* __restrict__ out)
{
  // A-tile: [64 rows][512 K] bf16, 16B-chunk XOR swizzle  (64 KB)
  __shared__ __align__(16) ushort sA[64 * 512];
  // B-tile: double-buffered [256 n][64 K] bf16, pre-swizzled in g_w  (2 x 32 KB)
  __shared__ __align__(16) ushort sB[2][256 * 64];
  __shared__ __align__(16) float  sRed[2][64 * 8];   // softmax cross-wave scratch

  const int tid  = threadIdx.x;
  const int w    = tid >> 6;       // wave 0..7, owns cols [w*32, w*32+32)
  const int lane = tid & 63;
  const int g4   = lane >> 4;
  const int l15  = lane & 15;
  const int sxor = l15 & 7;        // row&7 == n&7 == l15&7 for all frag rows
  const int rowBlk = blockIdx.x << 6;

  auto stageB = [&](int blkid, int buf) {
    const char* sb = (const char*)g_w + ((size_t)blkid << 15) + (w << 12) + (lane << 4);
    char* db = ((char*)&sB[buf][0]) + (w << 12);
#pragma unroll
    for (int i = 0; i < 4; ++i) {
      __builtin_amdgcn_global_load_lds(
          (const __attribute__((address_space(1))) void*)(sb + i * 1024),
          (__attribute__((address_space(3))) void*)(db + i * 1024),
          16, 0, 0);
    }
  };

  stageB(0, 0);   // phase 0, kb 0 -> buf 0

  { // stage A = [x | h] as bf16, swizzled
    const float4* xq = reinterpret_cast<const float4*>(x)  + (size_t)rowBlk * 64;
    const float4* hq = reinterpret_cast<const float4*>(hp) + (size_t)rowBlk * 64;
#pragma unroll
    for (int i = 0; i < 16; ++i) {
      int q   = tid + i * BDIM;        // 0..8191 quad index
      int row = q >> 7;
      int qc  = q & 127;
      float4 v = (qc < 64) ? xq[row * 64 + qc] : hq[row * 64 + qc - 64];
      int kE  = qc << 2;
      int swz = (kE >> 3) ^ (row & 7);
      ushort4 pk4;
      pk4.x = f2bf(v.x); pk4.y = f2bf(v.y); pk4.z = f2bf(v.z); pk4.w = f2bf(v.w);
      *reinterpret_cast<ushort4*>((char*)sA + (row << 10) + (swz << 4) + ((kE & 7) << 1)) = pk4;
    }
  }
  __syncthreads();

  float4v acc[4][2];
  float   zf[4][2][4];   // z gate, phase-1 result (C-layout positions match phase 3)
  float   hv[4][2][4];   // h_prev at C-layout positions (bf16-rounded)
  int cur = 0;

  for (int p = 0; p < 3; ++p) {
#pragma unroll
    for (int m = 0; m < 4; ++m)
#pragma unroll
      for (int r = 0; r < 2; ++r)
        acc[m][r] = (float4v){0.f, 0.f, 0.f, 0.f};

    for (int kb = 0; kb < 8; ++kb) {
      int blk = p * 8 + kb;
      if (blk < 23) stageB(blk + 1, cur ^ 1);   // prefetch next K-block (crosses phases)

      short8v afr[2][4], bfr[2][2];
#pragma unroll
      for (int s = 0; s < 2; ++s) {
#pragma unroll
        for (int m = 0; m < 4; ++m) {
          int row = m * 16 + l15;
          int swz = (kb * 8 + s * 4 + g4) ^ sxor;
          afr[s][m] = *reinterpret_cast<const short8v*>((const char*)sA + (row << 10) + (swz << 4));
        }
#pragma unroll
        for (int r = 0; r < 2; ++r) {
          int n   = (w << 5) + (r << 4) + l15;
          int swz = (s * 4 + g4) ^ sxor;
          bfr[s][r] = *reinterpret_cast<const short8v*>((const char*)&sB[cur][0] + (n << 7) + (swz << 4));
        }
      }
#pragma unroll
      for (int s = 0; s < 2; ++s)
#pragma unroll
        for (int m = 0; m < 4; ++m)
#pragma unroll
          for (int r = 0; r < 2; ++r)
            acc[m][r] = __builtin_amdgcn_mfma_f32_16x16x32_bf16(afr[s][m], bfr[s][r], acc[m][r], 0, 0, 0);

      __syncthreads();
      cur ^= 1;
    }

    if (p == 0) {
      // z = sigmoid(pre + b_z)
#pragma unroll
      for (int r = 0; r < 2; ++r) {
        float b = bz[(w << 5) + (r << 4) + l15];
#pragma unroll
        for (int m = 0; m < 4; ++m)
#pragma unroll
          for (int j = 0; j < 4; ++j)
            zf[m][r][j] = 1.f / (1.f + __expf(-(acc[m][r][j] + b)));
      }
    } else if (p == 1) {
      // t = tanh(pre) * v_a ; softmax over 256 cols per row ; attended = aw*h
      float vav[2];
      vav[0] = va[(w << 5) + l15];
      vav[1] = va[(w << 5) + 16 + l15];
#pragma unroll
      for (int m = 0; m < 4; ++m)
#pragma unroll
        for (int r = 0; r < 2; ++r)
#pragma unroll
          for (int j = 0; j < 4; ++j) {
            float s = acc[m][r][j];
            float t = 1.f - 2.f / (__expf(2.f * s) + 1.f);
            acc[m][r][j] = t * vav[r];
          }
      // wave-local row max (16-lane groups share a row set)
      float mx[4][4];
#pragma unroll
      for (int m = 0; m < 4; ++m)
#pragma unroll
        for (int j = 0; j < 4; ++j) {
          float v = fmaxf(acc[m][0][j], acc[m][1][j]);
          v = fmaxf(v, __shfl_xor(v, 1));
          v = fmaxf(v, __shfl_xor(v, 2));
          v = fmaxf(v, __shfl_xor(v, 4));
          v = fmaxf(v, __shfl_xor(v, 8));
          mx[m][j] = v;
        }
      if (l15 == 0) {
#pragma unroll
        for (int m = 0; m < 4; ++m)
#pragma unroll
          for (int j = 0; j < 4; ++j)
            sRed[0][((m * 16 + g4 * 4 + j) << 3) + w] = mx[m][j];
      }
      __syncthreads();
      float rmax[4][4], rsum[4][4];
#pragma unroll
      for (int m = 0; m < 4; ++m)
#pragma unroll
        for (int j = 0; j < 4; ++j) {
          int row = m * 16 + g4 * 4 + j;
          const float4* pr = reinterpret_cast<const float4*>(&sRed[0][row << 3]);
          float4 a = pr[0], b = pr[1];
          rmax[m][j] = fmaxf(fmaxf(fmaxf(a.x, a.y), fmaxf(a.z, a.w)),
                             fmaxf(fmaxf(b.x, b.y), fmaxf(b.z, b.w)));
        }
#pragma unroll
      for (int m = 0; m < 4; ++m)
#pragma unroll
        for (int j = 0; j < 4; ++j) {
          float e0 = __expf(acc[m][0][j] - rmax[m][j]);
          float e1 = __expf(acc[m][1][j] - rmax[m][j]);
          acc[m][0][j] = e0; acc[m][1][j] = e1;
          float sm = e0 + e1;
          sm += __shfl_xor(sm, 1);
          sm += __shfl_xor(sm, 2);
          sm += __shfl_xor(sm, 4);
          sm += __shfl_xor(sm, 8);
          rsum[m][j] = sm;
        }
      if (l15 == 0) {
#pragma unroll
        for (int m = 0; m < 4; ++m)
#pragma unroll
          for (int j = 0; j < 4; ++j)
            sRed[1][((m * 16 + g4 * 4 + j) << 3) + w] = rsum[m][j];
      }
      // load h (own positions) BEFORE overwriting h-half with attended
#pragma unroll
      for (int m = 0; m < 4; ++m)
#pragma unroll
        for (int r = 0; r < 2; ++r)
#pragma unroll
          for (int j = 0; j < 4; ++j) {
            int row = m * 16 + g4 * 4 + j;
            int cs  = (32 + (w << 2) + (r << 1) + (l15 >> 3)) ^ (row & 7);
            hv[m][r][j] = bf2f(sA[(row << 9) + (cs << 3) + sxor]);
          }
      __syncthreads();
#pragma unroll
      for (int m = 0; m < 4; ++m)
#pragma unroll
        for (int j = 0; j < 4; ++j) {
          int row = m * 16 + g4 * 4 + j;
          const float4* pr = reinterpret_cast<const float4*>(&sRed[1][row << 3]);
          float4 a = pr[0], b = pr[1];
          float s = (a.x + a.y) + (a.z + a.w) + (b.x + b.y) + (b.z + b.w);
          float inv = 1.f / s;
#pragma unroll
          for (int r = 0; r < 2; ++r) {
            float at = acc[m][r][j] * inv * hv[m][r][j];
            int cs = (32 + (w << 2) + (r << 1) + (l15 >> 3)) ^ (row & 7);
            sA[(row << 9) + (cs << 3) + sxor] = f2bf(at);
          }
        }
      __syncthreads();
    } else {
      // h~ = tanh(pre + b_h); h_t = (1-z)h + z h~
#pragma unroll
      for (int r = 0; r < 2; ++r) {
        float b = bh[(w << 5) + (r << 4) + l15];
#pragma unroll
        for (int m = 0; m < 4; ++m)
#pragma unroll
          for (int j = 0; j < 4; ++j) {
            float s  = acc[m][r][j] + b;
            float ht = 1.f - 2.f / (__expf(2.f * s) + 1.f);
            float z  = zf[m][r][j];
            float res = (1.f - z) * hv[m][r][j] + z * ht;
            int row = m * 16 + g4 * 4 + j;
            out[(size_t)(rowBlk + row) * 256 + (w << 5) + (r << 4) + l15] = res;
          }
      }
    }
  }
}

extern "C" void kernel_launch(void* const* d_in, const int* in_sizes, int n_in,
                              void* d_out, int out_size, void* d_ws, size_t ws_size,
                              hipStream_t stream)
{
  const float* x  = (const float*)d_in[0];
  const float* hp = (const float*)d_in[1];
  const float* Wz = (const float*)d_in[2];
  const float* Uz = (const float*)d_in[3];
  const float* bz = (const float*)d_in[4];
  const float* Wa = (const float*)d_in[5];
  const float* Ua = (const float*)d_in[6];
  const float* va = (const float*)d_in[7];
  const float* Wh = (const float*)d_in[8];
  const float* Uh = (const float*)d_in[9];
  const float* bh = (const float*)d_in[10];
  float* out = (float*)d_out;

  conv_w<<<dim3(192), dim3(256), 0, stream>>>(Wz, Uz, Wa, Ua, Wh, Uh);
  gru_fused<<<dim3(1024), dim3(BDIM), 0, stream>>>(x, hp, bz, va, bh, out);
}